// Round 6
// baseline (25546.518 us; speedup 1.0000x reference)
//
#include <hip/hip_runtime.h>

#define TT 512
#define BB 64
#define EE 300
#define HH 1024
#define GG 4096
#define NSLOT 33   // h ring slots: large reuse distance => stale-L2 lines evicted

// Workspace layout:
//   flags   256*4 B   (@0, padded to 1 KB)   per-block step flags
//   cstate  1024*64*4 B                      cell state [p][u][b]
//   hbuf    NSLOT x 256 KB, slot = t mod NSLOT, layout [kq][b][4]
//   mask    512*64*4 B                       [t][b]
//   xT      512*300*64*4 B = 39.3 MB         x transposed [t][e][b]

__device__ __forceinline__ float sigmf(float x) {
    return __fdividef(1.0f, 1.0f + __expf(-x));
}
__device__ __forceinline__ float tanhsf(float x) {
    float e = __expf(-2.0f * fabsf(x));
    float r = __fdividef(1.0f - e, 1.0f + e);
    return copysignf(r, x);
}

__global__ void mask_kernel(const int* __restrict__ seq, float* __restrict__ maskf) {
    int idx = blockIdx.x * 256 + threadIdx.x;   // covers 512*64
    int t = idx >> 6, b = idx & 63;
    maskf[idx] = (seq[b * TT + t] != 0) ? 1.0f : 0.0f;
}

// xT[t][e][b] = emb[seq[b][t]][e]  (block per t; LDS transpose, pad 305)
__global__ __launch_bounds__(256)
void xgather_kernel(const float* __restrict__ emb, const int* __restrict__ seq,
                    float* __restrict__ xT) {
    __shared__ float xrow[64 * 305];
    const int t = blockIdx.x, tid = threadIdx.x;
    const int r = tid >> 2, sub = tid & 3;
    const int row = seq[r * TT + t];
    for (int e = sub; e < EE; e += 4)
        xrow[r * 305 + e] = emb[row * EE + e];
    __syncthreads();
    float* dst = xT + (size_t)t * (EE * BB);
    for (int idx = tid; idx < EE * BB; idx += 256) {
        int e = idx >> 6, b = idx & 63;
        dst[idx] = xrow[b * 305 + e];
    }
}

// Persistent LSTM, one dispatch for all 512 steps. 256 WGs x 512 thr, 1/CU.
// KEY (r5 post-mortem): weight feeds moved OFF the DS pipe. R/W addresses are
// wave-uniform (block p, wave wu) -> readfirstlane forces uniformity -> the
// compiler emits s_load_dwordx4 (SMEM/K$) and v_fmac consumes the SGPR
// directly. The per-CU DS unit (was 4096 ds_read_b128/step ~ 13.7 us) now
// only carries zb reductions. R slice (64 KB/CU) stays L2-resident.
__global__ __launch_bounds__(512, 2)
void lstm_kernel(const float* __restrict__ xT, const float* __restrict__ rk,
                 const float* __restrict__ wk, const float* __restrict__ bias,
                 const float* __restrict__ maskf, float* __restrict__ hbuf,
                 float* __restrict__ cstate, unsigned int* __restrict__ flags,
                 float* __restrict__ out) {
    __shared__ float zb[8192];     // [wave][16][64] partials (zx then recurrent)
    __shared__ float zxbuf[2048];  // [2][16][64] reduced zx + bias, double buffer
    __shared__ float cs[256];      // [u][b] cell state
    __shared__ float hsh[256];     // h swizzle for coalesced publish
    const int tid = threadIdx.x;
    const int lane = tid & 63;
    const int wu = __builtin_amdgcn_readfirstlane(tid >> 6);  // uniform wave id
    const int p = blockIdx.x;
    const int p4 = p << 2;

    if (tid < 256) cs[tid] = cstate[(p << 8) + tid];
    float bb[4];
    if (wu < 4) {
#pragma unroll
        for (int gt = 0; gt < 4; ++gt)
            bb[gt] = bias[(gt << 10) + p4 + wu];
    }
    int slot = 0;
    int nslot = 1;
    float hown = 0.0f;   // h starts at 0 (hbuf slot 0 zeroed)
    const int fidx = (wu << 5) + (lane & 31);   // this wave's producer flags
    const int e0 = wu * 38;
    const int e1 = (e0 + 38 < EE) ? e0 + 38 : EE;
    __syncthreads();

    // ---- zx(t): partials -> zb, reduce (+bias) by waves 0-3; W via SMEM ----
#define ZX_COMPUTE(tn, bi) {                                                   \
        if ((tn) < TT) {                                                       \
            const float* xt = xT + (size_t)(tn) * (EE * BB);                   \
            float zacc[16];                                                    \
            _Pragma("unroll") for (int c = 0; c < 16; ++c) zacc[c] = 0.0f;     \
            _Pragma("unroll 2") for (int e = e0; e < e1; ++e) {                \
                float xv = xt[(e << 6) + lane];                                \
                const float* wr = wk + (size_t)e * GG + p4;   /* uniform */    \
                float4 q0 = *(const float4*)(wr);                              \
                float4 q1 = *(const float4*)(wr + 1024);                       \
                float4 q2 = *(const float4*)(wr + 2048);                       \
                float4 q3 = *(const float4*)(wr + 3072);                       \
                zacc[0]  = fmaf(xv, q0.x, zacc[0]);  zacc[1]  = fmaf(xv, q0.y, zacc[1]);  \
                zacc[2]  = fmaf(xv, q0.z, zacc[2]);  zacc[3]  = fmaf(xv, q0.w, zacc[3]);  \
                zacc[4]  = fmaf(xv, q1.x, zacc[4]);  zacc[5]  = fmaf(xv, q1.y, zacc[5]);  \
                zacc[6]  = fmaf(xv, q1.z, zacc[6]);  zacc[7]  = fmaf(xv, q1.w, zacc[7]);  \
                zacc[8]  = fmaf(xv, q2.x, zacc[8]);  zacc[9]  = fmaf(xv, q2.y, zacc[9]);  \
                zacc[10] = fmaf(xv, q2.z, zacc[10]); zacc[11] = fmaf(xv, q2.w, zacc[11]); \
                zacc[12] = fmaf(xv, q3.x, zacc[12]); zacc[13] = fmaf(xv, q3.y, zacc[13]); \
                zacc[14] = fmaf(xv, q3.z, zacc[14]); zacc[15] = fmaf(xv, q3.w, zacc[15]); \
            }                                                                  \
            _Pragma("unroll") for (int c = 0; c < 16; ++c)                     \
                zb[((wu << 4) + c) * 64 + lane] = zacc[c];                     \
        }                                                                      \
        __syncthreads();  /* S1 */                                             \
        if ((tn) < TT && wu < 4) {                                             \
            _Pragma("unroll") for (int gt = 0; gt < 4; ++gt) {                 \
                int c = (gt << 2) + wu;                                        \
                float s = bb[gt];                                              \
                _Pragma("unroll") for (int wp = 0; wp < 8; ++wp)               \
                    s += zb[((wp << 4) + c) * 64 + lane];                      \
                zxbuf[((bi) << 10) + (c << 6) + lane] = s;                     \
            }                                                                  \
        }                                                                      \
        __syncthreads();  /* S2 */                                             \
    }

    ZX_COMPUTE(0, 0)   // prologue: zx for step 0

    for (int t = 0; t < TT; ++t) {
        const float4* hp4 = (const float4*)(hbuf + (size_t)slot * 65536);
        float* hn = hbuf + (size_t)nslot * 65536;
        float m = maskf[(t << 6) + lane];

        ZX_COMPUTE(t + 1, (t + 1) & 1)     // fills the wait bubble below

        // per-wave wait: h^t from my 32 producers must be published
        if (t > 0) {
            unsigned int tgt = (unsigned int)t;
            while (!__all((int)(__hip_atomic_load(flags + fidx, __ATOMIC_RELAXED,
                                                  __HIP_MEMORY_SCOPE_AGENT) >= tgt)))
                __builtin_amdgcn_s_sleep(1);
        }
        __builtin_amdgcn_sched_barrier(0);  // keep h loads after the wait

        float acc[16];
#pragma unroll
        for (int c = 0; c < 16; ++c) acc[c] = 0.0f;
        const int kq0 = wu << 5;            // uniform
        float4 hv[8];
#pragma unroll
        for (int i = 0; i < 8; ++i) hv[i] = hp4[((kq0 + i) << 6) + lane];
        for (int g8 = 0; g8 < 4; ++g8) {    // 8-deep h prefetch ring
#pragma unroll
            for (int j = 0; j < 8; ++j) {
                float4 cur = hv[j];
                int kq = kq0 + (g8 << 3) + j;               // uniform
                if (g8 < 3) hv[j] = hp4[((kq + 8) << 6) + lane];
                const float* rp = rk + ((size_t)kq << 2) * GG + p4;  // uniform
#define LSTM_STEPK(kk, comp) { \
                const float* rkp = rp + (kk) * GG; \
                float4 r0 = *(const float4*)(rkp); \
                float4 r1 = *(const float4*)(rkp + 1024); \
                float4 r2 = *(const float4*)(rkp + 2048); \
                float4 r3 = *(const float4*)(rkp + 3072); \
                acc[0]  = fmaf(comp, r0.x, acc[0]);  acc[1]  = fmaf(comp, r0.y, acc[1]);  \
                acc[2]  = fmaf(comp, r0.z, acc[2]);  acc[3]  = fmaf(comp, r0.w, acc[3]);  \
                acc[4]  = fmaf(comp, r1.x, acc[4]);  acc[5]  = fmaf(comp, r1.y, acc[5]);  \
                acc[6]  = fmaf(comp, r1.z, acc[6]);  acc[7]  = fmaf(comp, r1.w, acc[7]);  \
                acc[8]  = fmaf(comp, r2.x, acc[8]);  acc[9]  = fmaf(comp, r2.y, acc[9]);  \
                acc[10] = fmaf(comp, r2.z, acc[10]); acc[11] = fmaf(comp, r2.w, acc[11]); \
                acc[12] = fmaf(comp, r3.x, acc[12]); acc[13] = fmaf(comp, r3.y, acc[13]); \
                acc[14] = fmaf(comp, r3.z, acc[14]); acc[15] = fmaf(comp, r3.w, acc[15]); }
                LSTM_STEPK(0, cur.x)
                LSTM_STEPK(1, cur.y)
                LSTM_STEPK(2, cur.z)
                LSTM_STEPK(3, cur.w)
#undef LSTM_STEPK
            }
        }
#pragma unroll
        for (int c = 0; c < 16; ++c) zb[((wu << 4) + c) * 64 + lane] = acc[c];
        __syncthreads();                               // S3: recurrent partials done
        if (wu < 4) {
            float z[4];
#pragma unroll
            for (int gt = 0; gt < 4; ++gt) {
                int c = (gt << 2) + wu;
                float s = zxbuf[((t & 1) << 10) + (c << 6) + lane];
#pragma unroll
                for (int wp = 0; wp < 8; ++wp) s += zb[((wp << 4) + c) * 64 + lane];
                z[gt] = s;
            }
            float fi = sigmf(z[0]);
            float ff = sigmf(z[1]);
            float fg = tanhsf(z[2]);
            float fo = sigmf(z[3]);
            float co = cs[(wu << 6) + lane];
            float cn = fmaf(ff, co, fi * fg);
            cn = fmaf(m, cn - co, co);                 // masked c update
            cs[(wu << 6) + lane] = cn;
            float hc = fo * tanhsf(cn);
            hown = fmaf(m, hc - hown, hown);           // masked h update
            hsh[(lane << 2) + wu] = hown;
        }
        __syncthreads();                               // S4: hsh ready
        if (tid < 256)                                 // coalesced agent-scope publish
            __hip_atomic_store(hn + (p << 8) + tid, hsh[tid],
                               __ATOMIC_RELAXED, __HIP_MEMORY_SCOPE_AGENT);
        __syncthreads();                               // S5: vmcnt(0), h visible
        if (tid == 0)
            __hip_atomic_store(flags + p, (unsigned int)(t + 1),
                               __ATOMIC_RELAXED, __HIP_MEMORY_SCOPE_AGENT);
        slot = nslot;
        nslot = (nslot + 1 == NSLOT) ? 0 : nslot + 1;
    }
#undef ZX_COMPUTE
    if (tid < 256) cstate[(p << 8) + tid] = cs[tid];
    if (wu < 4) zb[(wu << 6) + lane] = hown;
    __syncthreads();
    if (tid < 64) {
        float4 v = make_float4(zb[tid], zb[64 + tid], zb[128 + tid], zb[192 + tid]);
        *(float4*)(out + tid * HH + p4) = v;
    }
}

extern "C" void kernel_launch(void* const* d_in, const int* in_sizes, int n_in,
                              void* d_out, int out_size, void* d_ws, size_t ws_size,
                              hipStream_t stream) {
    const float* emb  = (const float*)d_in[0];
    const float* wk   = (const float*)d_in[1];
    const float* rk   = (const float*)d_in[2];
    const float* bias = (const float*)d_in[3];
    const int*   seq  = (const int*)d_in[4];
    float* out = (float*)d_out;
    char* ws = (char*)d_ws;

    const size_t off_cstate = 1024;
    const size_t off_hbuf   = off_cstate + 262144;
    const size_t off_mask   = off_hbuf + (size_t)NSLOT * 262144;
    const size_t off_xT     = off_mask + 131072;
    unsigned int* flags = (unsigned int*)ws;
    float* cstate = (float*)(ws + off_cstate);
    float* hbuf   = (float*)(ws + off_hbuf);
    float* maskf  = (float*)(ws + off_mask);
    float* xT     = (float*)(ws + off_xT);

    // zero flags + cstate + hbuf slot 0 (contiguous prefix)
    hipMemsetAsync(ws, 0, off_hbuf + 262144, stream);
    mask_kernel<<<128, 256, 0, stream>>>(seq, maskf);
    xgather_kernel<<<TT, 256, 0, stream>>>(emb, seq, xT);
    lstm_kernel<<<256, 512, 0, stream>>>(xT, rk, wk, bias, maskf, hbuf, cstate,
                                         flags, out);
}

// Round 7
// 1880.033 us; speedup vs baseline: 13.5883x; 13.5883x over previous
//
#include <hip/hip_runtime.h>

#define TT 512
#define BB 64
#define EE 300
#define HH 1024
#define GG 4096
#define NSLOT 33   // h ring slots: drift <= ~2 steps, so no WAR; stale L2 evicted

typedef _Float16 f16x8 __attribute__((ext_vector_type(8)));
typedef float f32x4 __attribute__((ext_vector_type(4)));

// Workspace layout (bytes):
//   flags  @0, 1 KB                      per-block step flags
//   hbuf   @1024, NSLOT x 131072        h ring, f16, [kb32][quad4][b64][j8]
//   mask   @off_mask, 512*64*4           [t][b] f32
//   xA     @off_xA, 512*20480*2          x in MFMA-A layout [t][kb10][quad][b][j] f16
// total ~25.4 MB

__device__ __forceinline__ float sigmf(float x) {
    return __fdividef(1.0f, 1.0f + __expf(-x));
}
__device__ __forceinline__ float tanhsf(float x) {
    float e = __expf(-2.0f * fabsf(x));
    float r = __fdividef(1.0f - e, 1.0f + e);
    return copysignf(r, x);
}

__global__ void mask_kernel(const int* __restrict__ seq, float* __restrict__ maskf) {
    int idx = blockIdx.x * 256 + threadIdx.x;   // covers 512*64
    int t = idx >> 6, b = idx & 63;
    maskf[idx] = (seq[b * TT + t] != 0) ? 1.0f : 0.0f;
}

// xA[t][kb][quad][b][j] = f16(emb[seq[b][t]][e]), e = kb*32+quad*8+j, 0-pad e>=300
__global__ __launch_bounds__(256)
void xgather_kernel(const float* __restrict__ emb, const int* __restrict__ seq,
                    _Float16* __restrict__ xA) {
    __shared__ float xrow[64 * 305];
    const int t = blockIdx.x, tid = threadIdx.x;
    const int r = tid >> 2, sub = tid & 3;
    const int row = seq[r * TT + t];
    for (int e = sub; e < EE; e += 4)
        xrow[r * 305 + e] = emb[row * EE + e];
    __syncthreads();
    unsigned int* dst = (unsigned int*)(xA + (size_t)t * 20480);
    for (int idx = tid; idx < 10240; idx += 256) {
        int el = idx << 1;
        int j = el & 7, b = (el >> 3) & 63, quad = (el >> 9) & 3, kb = el >> 11;
        int e = (kb << 5) + (quad << 3) + j;
        union { _Float16 h[2]; unsigned int u; } pk;
        pk.h[0] = (e < EE)     ? (_Float16)xrow[b * 305 + e]     : (_Float16)0.f;
        pk.h[1] = (e + 1 < EE) ? (_Float16)xrow[b * 305 + e + 1] : (_Float16)0.f;
        dst[idx] = pk.u;
    }
}

// Persistent LSTM, one dispatch, 512 steps. 256 WGs x 512 thr (1/CU, 86KB LDS).
// r6 post-mortem: weights stay LDS-resident (fetched once), but fed to the
// MATRIX pipe: R/W pre-packed into f16 MFMA B-fragments (lane-distinct 16B
// ds_reads, 4/wave/step vs 4096 broadcast b128/CU in r5). h published f16 in
// A-fragment layout; x.W merged into the same accumulators before the wait.
// A/B k-permutation cancels (same packing both sides); C/D layout HW-verified.
__global__ __launch_bounds__(512, 2)
void lstm_kernel(const _Float16* __restrict__ xA, const float* __restrict__ rk,
                 const float* __restrict__ wk, const float* __restrict__ bias,
                 const float* __restrict__ maskf, _Float16* __restrict__ hbuf,
                 unsigned int* __restrict__ flags, float* __restrict__ out) {
    __shared__ _Float16 RbL[16384];   // [kb32][quad][c16][j8] B-frags of R
    __shared__ _Float16 WbL[5120];    // [kb10][quad][c16][j8] B-frags of W
    __shared__ float zb[8704];        // [8w][16c] rows, stride 68 (bank-safe)
    __shared__ float cs[2048];        // 256 used; padding forces 1 block/CU
    __shared__ _Float16 hshh[256];    // f16 publish staging [b][uu]
    const int tid = threadIdx.x;
    const int lane = tid & 63;
    const int w = tid >> 6;
    const int p = blockIdx.x;
    const int p4 = p << 2;
    const int cc = lane & 15, quad = lane >> 4;

    // pack R slice (k x 16 cols) into B-fragment order, f16, once
    for (int i = tid; i < 16384; i += 512) {
        int k = i >> 4, c = i & 15;
        float v = rk[k * GG + ((c >> 2) << 10) + p4 + (c & 3)];
        RbL[((k >> 5) << 9) + (((k >> 3) & 3) << 7) + (c << 3) + (k & 7)] = (_Float16)v;
    }
    for (int i = tid; i < 5120; i += 512) {
        int e = i >> 4, c = i & 15;
        float v = (e < EE) ? wk[e * GG + ((c >> 2) << 10) + p4 + (c & 3)] : 0.f;
        WbL[((e >> 5) << 9) + (((e >> 3) & 3) << 7) + (c << 3) + (e & 7)] = (_Float16)v;
    }
    if (tid < 256) cs[tid] = 0.f;
    float bb[4];
    if (w < 4) {
#pragma unroll
        for (int gt = 0; gt < 4; ++gt)
            bb[gt] = bias[(gt << 10) + p4 + w];
    }
    int slot = 0, nslot = 1;
    float hown = 0.0f;
    const int fidx = (w << 5) + (lane & 31);   // wave w's producers: p in [32w,32w+32)
    const f16x8* RbH = (const f16x8*)RbL;
    const f16x8* WbH = (const f16x8*)WbL;
    __syncthreads();

    for (int t = 0; t < TT; ++t) {
        float m = maskf[(t << 6) + lane];
        f32x4 acc[4];
#pragma unroll
        for (int mt = 0; mt < 4; ++mt) acc[mt] = (f32x4){0.f, 0.f, 0.f, 0.f};

        // ---- x.W part: no h dependency, runs before/through the wait ----
        const f16x8* xA8 = (const f16x8*)(xA + (size_t)t * 20480);
        {
            int kb = w;
            f16x8 bf = WbH[(kb << 6) + (quad << 4) + cc];
#pragma unroll
            for (int mt = 0; mt < 4; ++mt) {
                f16x8 af = xA8[(kb << 8) + (quad << 6) + (mt << 4) + cc];
                acc[mt] = __builtin_amdgcn_mfma_f32_16x16x32_f16(af, bf, acc[mt], 0, 0, 0);
            }
        }
        if (w < 2) {
            int kb = 8 + w;
            f16x8 bf = WbH[(kb << 6) + (quad << 4) + cc];
#pragma unroll
            for (int mt = 0; mt < 4; ++mt) {
                f16x8 af = xA8[(kb << 8) + (quad << 6) + (mt << 4) + cc];
                acc[mt] = __builtin_amdgcn_mfma_f32_16x16x32_f16(af, bf, acc[mt], 0, 0, 0);
            }
        }

        // ---- wait: my 32 producers must have published h^t ----
        if (t > 0) {
            unsigned int tgt = (unsigned int)t;
            while (!__all((int)(__hip_atomic_load(flags + fidx, __ATOMIC_RELAXED,
                                                  __HIP_MEMORY_SCOPE_AGENT) >= tgt)))
                __builtin_amdgcn_s_sleep(1);
        }
        __builtin_amdgcn_sched_barrier(0);   // keep h loads after the wait

        // ---- recurrent h.R: wave w owns k in [128w,128w+128) = kb 4w..4w+3 ----
        const f16x8* hA8 = (const f16x8*)(hbuf + (size_t)slot * 65536);
#pragma unroll
        for (int kc = 0; kc < 4; ++kc) {
            int kb = (w << 2) + kc;
            f16x8 bf = RbH[(kb << 6) + (quad << 4) + cc];
#pragma unroll
            for (int mt = 0; mt < 4; ++mt) {
                f16x8 af = hA8[(kb << 8) + (quad << 6) + (mt << 4) + cc];
                acc[mt] = __builtin_amdgcn_mfma_f32_16x16x32_f16(af, bf, acc[mt], 0, 0, 0);
            }
        }
        // D layout: col c = lane&15, b = 16*mt + quad*4 + reg
#pragma unroll
        for (int mt = 0; mt < 4; ++mt)
            *(f32x4*)(zb + ((w << 4) + cc) * 68 + (mt << 4) + (quad << 2)) = acc[mt];
        __syncthreads();                               // S3: partials done
        if (w < 4) {
            float z[4];
#pragma unroll
            for (int gt = 0; gt < 4; ++gt) {
                int c = (gt << 2) + w;
                float s = bb[gt];
#pragma unroll
                for (int wp = 0; wp < 8; ++wp) s += zb[((wp << 4) + c) * 68 + lane];
                z[gt] = s;
            }
            float fi = sigmf(z[0]);
            float ff = sigmf(z[1]);
            float fg = tanhsf(z[2]);
            float fo = sigmf(z[3]);
            float co = cs[(w << 6) + lane];
            float cn = fmaf(ff, co, fi * fg);
            cn = fmaf(m, cn - co, co);                 // masked c update
            cs[(w << 6) + lane] = cn;
            float hc = fo * tanhsf(cn);
            hown = fmaf(m, hc - hown, hown);           // masked h update (f32 local)
            hshh[(lane << 2) + w] = (_Float16)hown;
        }
        __syncthreads();                               // S4: hshh ready
        if (tid < 64) {                                // publish 4 f16 (8 B) per batch
            unsigned long long hv = ((const unsigned long long*)hshh)[lane];
            size_t el = (size_t)nslot * 65536 + ((size_t)(p >> 3) << 11) +
                        ((size_t)((p >> 1) & 3) << 9) + (lane << 3) + ((p & 1) << 2);
            __hip_atomic_store((unsigned long long*)(hbuf + el), hv,
                               __ATOMIC_RELAXED, __HIP_MEMORY_SCOPE_AGENT);
        }
        __syncthreads();                               // S5: vmcnt(0), h visible
        if (tid == 0)
            __hip_atomic_store(flags + p, (unsigned int)(t + 1),
                               __ATOMIC_RELAXED, __HIP_MEMORY_SCOPE_AGENT);
        slot = nslot;
        nslot = (nslot + 1 == NSLOT) ? 0 : nslot + 1;
    }
    // final h -> out (f32 path, hown is exact f32 state)
    if (w < 4) zb[(w << 6) + lane] = hown;
    __syncthreads();
    if (tid < 64) {
        float4 v = make_float4(zb[tid], zb[64 + tid], zb[128 + tid], zb[192 + tid]);
        *(float4*)(out + tid * HH + p4) = v;
    }
}

extern "C" void kernel_launch(void* const* d_in, const int* in_sizes, int n_in,
                              void* d_out, int out_size, void* d_ws, size_t ws_size,
                              hipStream_t stream) {
    const float* emb  = (const float*)d_in[0];
    const float* wk   = (const float*)d_in[1];
    const float* rk   = (const float*)d_in[2];
    const float* bias = (const float*)d_in[3];
    const int*   seq  = (const int*)d_in[4];
    float* out = (float*)d_out;
    char* ws = (char*)d_ws;

    const size_t off_hbuf = 1024;
    const size_t off_mask = off_hbuf + (size_t)NSLOT * 131072;   // f16 slots, 128 KB
    const size_t off_xA   = off_mask + 131072;
    unsigned int* flags = (unsigned int*)ws;
    _Float16* hbuf  = (_Float16*)(ws + off_hbuf);
    float*    maskf = (float*)(ws + off_mask);
    _Float16* xA    = (_Float16*)(ws + off_xA);

    // zero flags + hbuf slot 0 (contiguous prefix); ws is re-poisoned each call
    hipMemsetAsync(ws, 0, off_hbuf + 131072, stream);
    mask_kernel<<<128, 256, 0, stream>>>(seq, maskf);
    xgather_kernel<<<TT, 256, 0, stream>>>(emb, seq, xA);
    lstm_kernel<<<256, 512, 0, stream>>>(xA, rk, wk, bias, maskf, hbuf, flags, out);
}